// Round 10
// baseline (268.338 us; speedup 1.0000x reference)
//
#include <hip/hip_runtime.h>
#include <cfloat>
#include <math.h>

// Exact-replication KNN (k=10, +self) + rank-column gather max-pool.
// NUMERICS FROZEN (R3 pass, absmax 0.0): fp32 chains
//   sq  = fma(z,z, fma(y,y, rn(x*x)))
//   dot = fma(z,z', fma(y,y', rn(x*x')))
//   d   = fma(dot, -2, rn(sq_i+sq_j))    [== rn(sum - rn(2*dot)), 2*dot exact]
// Selection order = jax top_k = ascending lexicographic (d, orig_idx) —
// proven order-independent in R8/R9 (absmax 0.0, nondeterministic scatter).
//
// Round 20: GATE-AND-APPEND cooperative blocks. knn is 3.4x tail-dominated
// (mean wave 35 us vs wall 119) and the tail wave's survivor scan is
// irreducible for ONE wave. R15's split failed because every wave paid the
// k=11 serial-insert floor. Now scanning waves keep NO lists: per tile they
// compute 4 distances, ballot vs the FIXED radix-exact gate wmax0 (R14:
// usually == final 11th), and append passing (d,idx) to per-query LDS
// queues (wave-aggregated atomicAdd; appends are rare and order-free).
// The serial top-11 build happens ONCE per query in a merge phase: radix-
// select the queue's 11th, then the UNCHANGED proven sorted-insert over
// ~11+ties entries. Exact: gate >= true 11th, append set unique, merge
// reproduces lex top-11 bit-identically. QPB=4, grid 8192 (4x oversub ->
// streaming rebalances); 4 waves split the survivor list stride-4.
// Overflow (cap 384/query) -> exact serial fallback (never expected).
// R19 post-mortem: interleaved insert chains regressed (119->140; bigger
// loop body beat the latency win) - third proof the R16 insert form is
// locally optimal; it is reused verbatim in the merge. Prepass = R16.

#define N_PTS    16384
#define C_FEAT   64
#define KK       11
#define NCELLS   4096                 // 16^3 Morton cells
#define TILE     128                  // sorted points per tile
#define NTILES   (N_PTS / TILE)       // 128
#define WQ       4
#define NWAVES   4
#define NTHREADS (NWAVES * 64)
#define QPB      WQ                   // queries per BLOCK (cooperative)
#define QCAP     384                  // queue slots per query

// d_ws layout (bytes)
#define WS_CAND  0                            // float4[2][N_PTS]   512 KB
#define WS_AABB  (WS_CAND + 2*N_PTS*16)       // float[2][NTILES][6]  6 KB
#define WS_HIST  (WS_AABB + 2*NTILES*6*4)     // int[2][NCELLS]      32 KB

__device__ __forceinline__ int cell_of(float x, float y, float z) {
    int cx = (int)floorf((x + 4.5f) * (16.0f / 9.0f));
    int cy = (int)floorf((y + 4.5f) * (16.0f / 9.0f));
    int cz = (int)floorf((z + 4.5f) * (16.0f / 9.0f));
    cx = min(15, max(0, cx));
    cy = min(15, max(0, cy));
    cz = min(15, max(0, cz));
    int m = 0;
    #pragma unroll
    for (int b = 0; b < 4; ++b)
        m |= (((cx >> b) & 1) << (3 * b)) |
             (((cy >> b) & 1) << (3 * b + 1)) |
             (((cz >> b) & 1) << (3 * b + 2));
    return m;
}

// 128 blocks x 256 thr, one point per thread. Global atomics into hist
// (pre-zeroed by hipMemsetAsync).
__global__ __launch_bounds__(256) void hist_kernel(
    const float* __restrict__ src_c, const float* __restrict__ tgt_c,
    int* __restrict__ hist)
{
    const int inst = blockIdx.x >> 6;           // 64 blocks per instance
    const float* __restrict__ coords = inst ? tgt_c : src_c;
    int* __restrict__ h = hist + inst * NCELLS;
    const int p = ((blockIdx.x & 63) << 8) + threadIdx.x;
    const float* c = coords + (size_t)p * 3;
    atomicAdd(&h[cell_of(c[0], c[1], c[2])], 1);
}

// One block per instance. Barrier scan; leaves h[cell] = exclusive base.
__global__ __launch_bounds__(1024) void scan_kernel(int* __restrict__ hist)
{
    const int inst = blockIdx.x;
    int* __restrict__ h = hist + inst * NCELLS;
    __shared__ int sd[1024];
    const int t = threadIdx.x;

    int v[4], ssum = 0;
    #pragma unroll
    for (int j = 0; j < 4; ++j) { v[j] = h[t * 4 + j]; ssum += v[j]; }
    sd[t] = ssum;
    __syncthreads();
    for (int off = 1; off < 1024; off <<= 1) {
        const int x = (t >= off) ? sd[t - off] : 0;
        __syncthreads();
        sd[t] += x;
        __syncthreads();
    }
    int base = sd[t] - ssum;
    #pragma unroll
    for (int j = 0; j < 4; ++j) { h[t * 4 + j] = base; base += v[j]; }
}

// 128 blocks x 256 thr. dst = atomicAdd(write-pointer). Within-cell order is
// nondeterministic — exactly as R8-R19 (selection proven order-independent).
__global__ __launch_bounds__(256) void scatter_kernel(
    const float* __restrict__ src_c, const float* __restrict__ tgt_c,
    int* __restrict__ hist, float4* __restrict__ cand)
{
    const int inst = blockIdx.x >> 6;
    const float* __restrict__ coords = inst ? tgt_c : src_c;
    int* __restrict__ h = hist + inst * NCELLS;
    float4* __restrict__ cb = cand + inst * N_PTS;
    const int p = ((blockIdx.x & 63) << 8) + threadIdx.x;
    const float* c = coords + (size_t)p * 3;
    const float x = c[0], y = c[1], z = c[2];
    const int dst = atomicAdd(&h[cell_of(x, y, z)], 1);
    cb[dst] = make_float4(x, y, z, __int_as_float(p));
}

__global__ void aabb_kernel(const float4* __restrict__ cand,
                            float* __restrict__ aabb) {
    const int it = blockIdx.x;                 // inst*NTILES + tile
    const int base = (it / NTILES) * N_PTS + (it % NTILES) * TILE;
    const int lane = threadIdx.x;              // 64 threads, 2 pts each
    float4 a = cand[base + lane], b = cand[base + 64 + lane];
    float mnx = fminf(a.x, b.x), mny = fminf(a.y, b.y), mnz = fminf(a.z, b.z);
    float mxx = fmaxf(a.x, b.x), mxy = fmaxf(a.y, b.y), mxz = fmaxf(a.z, b.z);
    #pragma unroll
    for (int off = 1; off < 64; off <<= 1) {
        mnx = fminf(mnx, __shfl_xor(mnx, off));
        mny = fminf(mny, __shfl_xor(mny, off));
        mnz = fminf(mnz, __shfl_xor(mnz, off));
        mxx = fmaxf(mxx, __shfl_xor(mxx, off));
        mxy = fmaxf(mxy, __shfl_xor(mxy, off));
        mxz = fmaxf(mxz, __shfl_xor(mxz, off));
    }
    if (lane == 0) {
        aabb[it * 6 + 0] = mnx; aabb[it * 6 + 1] = mny; aabb[it * 6 + 2] = mnz;
        aabb[it * 6 + 3] = mxx; aabb[it * 6 + 4] = mxy; aabb[it * 6 + 5] = mxz;
    }
}

// Frozen distance chain for candidate C vs query q (do not reorder).
#define DIST_TO(C, q, dout)                                                 \
  { const float csq_ = __fmaf_rn((C).z, (C).z, __fmaf_rn((C).y, (C).y,      \
                                 __fmul_rn((C).x, (C).x)));                 \
    float dot_ = __fmul_rn((C).x, qx[q]);                                   \
    dot_ = __fmaf_rn((C).y, qy[q], dot_);                                   \
    dot_ = __fmaf_rn((C).z, qz[q], dot_);                                   \
    (dout) = __fmaf_rn(dot_, -2.0f, __fadd_rn(qsq[q], csq_)); }

// Gate-and-append one 64-candidate batch vs the block's 4 queries.
// Passing (d, idx) pairs go to per-query LDS queues; no lists, no serial
// loops in the scan path. Wave-aggregated LDS atomicAdd reservation.
#define APPEND_BATCH(C)                                                     \
  {                                                                         \
    const float cx = (C).x, cy = (C).y, cz = (C).z;                         \
    const int corig = __float_as_int((C).w);                                \
    const float csq = __fmaf_rn(cz, cz, __fmaf_rn(cy, cy,                   \
                                __fmul_rn(cx, cx)));                        \
    _Pragma("unroll")                                                       \
    for (int q = 0; q < WQ; ++q) {                                          \
      float dot = __fmul_rn(cx, qx[q]);                                     \
      dot = __fmaf_rn(cy, qy[q], dot);                                      \
      dot = __fmaf_rn(cz, qz[q], dot);                                      \
      const float sum = __fadd_rn(qsq[q], csq);                             \
      const float d = __fmaf_rn(dot, -2.0f, sum);                           \
      const unsigned long long m = __ballot(d <= wgate[q]);                 \
      if (m) {                                                              \
        const int leader = (int)__builtin_ctzll(m);                         \
        const int cnt = (int)__popcll(m);                                   \
        int rbase = 0;                                                      \
        if (lane == leader) rbase = atomicAdd(&qcur[q], cnt);               \
        rbase = __builtin_amdgcn_readlane(rbase, leader);                   \
        const int off = rbase +                                             \
            (int)__popcll(m & ((1ull << lane) - 1ull));                     \
        if (((m >> lane) & 1ull) && off < QCAP) {                           \
            qdq[q][off] = d; qiq[q][off] = corig;                           \
        }                                                                   \
        if (lane == leader && rbase + cnt > QCAP) qovf[q] = 1;              \
      }                                                                     \
    }                                                                       \
  }

// One serial insert step for the SINGLE-query merge list (lanes 0..10 of
// the wave hold the sorted lex list) — the R16-proven logic verbatim with
// ingrp -> (lane < KK), rank -> lane.
#define INS1(D, I, M)                                                       \
    {                                                                       \
      const int sl = (int)__builtin_ctzll(M);                               \
      M &= M - 1;                                                           \
      const float nd = __int_as_float(__builtin_amdgcn_readlane(            \
          __float_as_int(D), sl));                                          \
      if (nd <= worstm) {                                                   \
        const int ni = __builtin_amdgcn_readlane((I), sl);                  \
        const float pld = __int_as_float(                                   \
            __builtin_amdgcn_ds_bpermute(upaddr, __float_as_int(ld)));      \
        const int pli = __builtin_amdgcn_ds_bpermute(upaddr, li);           \
        const bool gt = (ld > nd) || (ld == nd && li > ni);                 \
        if (lane < KK && gt) {                                              \
          const bool pgt = (pld > nd) || (pld == nd && pli > ni);           \
          const bool fst = (lane == 0) || (!pgt);                           \
          ld = fst ? nd : pld;                                              \
          li = fst ? ni : pli;                                              \
        }                                                                   \
        worstm = fminf(worstm,                                              \
            __int_as_float(__builtin_amdgcn_readlane(                       \
                __float_as_int(ld), KK - 1)));                              \
      }                                                                     \
    }

__global__ __launch_bounds__(NTHREADS) void knn_pool_kernel(
    const float* __restrict__ src_f, const float* __restrict__ tgt_f,
    const float4* __restrict__ cand, const float* __restrict__ aabb,
    float* __restrict__ out)
{
    const int inst = blockIdx.x & 1;
    const float* __restrict__ feats = inst ? tgt_f : src_f;
    float* __restrict__ outb = out + (size_t)inst * N_PTS * (2 * C_FEAT);
    const float4* __restrict__ cd = cand + inst * N_PTS;

    const int tid = threadIdx.x, wave = tid >> 6, lane = tid & 63;
    const int upaddr = ((lane + 63) & 63) << 2;   // ds_bpermute: lane-1

    __shared__ float sab[NTILES * 6];     // 3 KB
    __shared__ unsigned slist[NTILES];    // packed (lb|tile), 512 B
    __shared__ int nsurv_sh;
    __shared__ float qdq[WQ][QCAP];       // 6 KB  per-query (d) queue
    __shared__ int   qiq[WQ][QCAP];       // 6 KB  per-query (idx) queue
    __shared__ int   qcur[WQ], qovf[WQ];

    for (int i = tid; i < NTILES * 6; i += NTHREADS)
        sab[i] = aabb[inst * NTILES * 6 + i];
    if (tid < WQ) { qcur[tid] = 0; qovf[tid] = 0; }
    __syncthreads();

    const int qbase = (blockIdx.x >> 1) * QPB;    // block's 4 sorted rows
    float qx[WQ], qy[WQ], qz[WQ], qsq[WQ];
    int qor[WQ]; float wgate[WQ];
    float wqmnx = FLT_MAX, wqmny = FLT_MAX, wqmnz = FLT_MAX;
    float wqmxx = -FLT_MAX, wqmxy = -FLT_MAX, wqmxz = -FLT_MAX;
    #pragma unroll
    for (int q = 0; q < WQ; ++q) {
        const float4 c = cd[qbase + q];
        qx[q] = c.x; qy[q] = c.y; qz[q] = c.z;
        qor[q] = __float_as_int(c.w);
        qsq[q] = __fmaf_rn(c.z, c.z, __fmaf_rn(c.y, c.y, __fmul_rn(c.x, c.x)));
        wqmnx = fminf(wqmnx, c.x); wqmxx = fmaxf(wqmxx, c.x);
        wqmny = fminf(wqmny, c.y); wqmxy = fmaxf(wqmxy, c.y);
        wqmnz = fminf(wqmnz, c.z); wqmxz = fmaxf(wqmxz, c.z);
    }

    const int ownt = qbase / TILE;   // tile containing the queries (4 | 128)

    // ---- own tile: radix-select exact 11th distance (ALL waves, cheap) --
    {
        const float4 c0 = cd[ownt * TILE + lane];
        const float4 c1 = cd[ownt * TILE + 64 + lane];
        unsigned k0[WQ], k1[WQ], pk[WQ];
        #pragma unroll
        for (int q = 0; q < WQ; ++q) {
            float da, db;
            DIST_TO(c0, q, da);
            DIST_TO(c1, q, db);
            const unsigned b0 = __float_as_uint(da), b1 = __float_as_uint(db);
            k0[q] = b0 ^ (((unsigned)((int)b0 >> 31)) | 0x80000000u);
            k1[q] = b1 ^ (((unsigned)((int)b1 >> 31)) | 0x80000000u);
            pk[q] = 0u;
        }
        for (int b = 31; b >= 0; --b) {
            #pragma unroll
            for (int q = 0; q < WQ; ++q) {
                const unsigned mid = pk[q] | (1u << b);
                const int cnt = (int)__popcll(__ballot(k0[q] < mid))
                              + (int)__popcll(__ballot(k1[q] < mid));
                if (cnt < KK) pk[q] = mid;
            }
        }
        #pragma unroll
        for (int q = 0; q < WQ; ++q) {
            const unsigned p = pk[q];
            wgate[q] = __uint_as_float(
                (p & 0x80000000u) ? (p ^ 0x80000000u) : ~p);
        }

        // wave 0: append own tile (>=11 entries per query by construction)
        // + build the zigzag survivor list with the fixed block gate.
        if (wave == 0) {
            APPEND_BATCH(c0);
            APPEND_BATCH(c1);

            const float wmax0 = fmaxf(fmaxf(wgate[0], wgate[1]),
                                      fmaxf(wgate[2], wgate[3]));
            int ns0 = 0;
            #pragma unroll
            for (int g = 0; g < 4; ++g) {
                const int p = g * 64 + lane;
                const int o = (p >> 1) + 1;
                const int t = (p & 1) ? (ownt - o) : (ownt + o);
                bool ok = (t >= 0) && (t < NTILES);
                float lb = 0.0f;
                if (ok) {
                    const float dx = fmaxf(0.f, fmaxf(sab[t*6+0] - wqmxx, wqmnx - sab[t*6+3]));
                    const float dy = fmaxf(0.f, fmaxf(sab[t*6+1] - wqmxy, wqmny - sab[t*6+4]));
                    const float dz = fmaxf(0.f, fmaxf(sab[t*6+2] - wqmxz, wqmnz - sab[t*6+5]));
                    lb = dx * dx;
                    lb = fmaf(dy, dy, lb);
                    lb = fmaf(dz, dz, lb);
                    ok = (lb - 1e-3f) <= wmax0;   // margin >> fp32 error
                }
                const unsigned long long mk = __ballot(ok);
                if (ok) {
                    const int idx = ns0 + (int)__popcll(mk & ((1ull << lane) - 1ull));
                    slist[idx] = (__float_as_uint(lb) & 0xFFFFFF00u) | (unsigned)t;
                }
                ns0 += (int)__popcll(mk);
            }
            if (lane == 0) nsurv_sh = ns0;
        }
    }
    __syncthreads();
    const int ns = nsurv_sh;

    // ---- scan: wave w appends slots w, w+4, ... (ping-pong prefetch) ----
    // Gate fixed at wgate (== build gate) -> every listed slot processed.
    {
        float4 A0, A1, B0, B1;
        {
            const int ta = (wave < ns) ? (int)(slist[wave] & 0xFFu) : ownt;
            A0 = cd[ta * TILE + lane]; A1 = cd[ta * TILE + 64 + lane];
            const int tb = (wave + 4 < ns) ? (int)(slist[wave + 4] & 0xFFu) : ownt;
            B0 = cd[tb * TILE + lane]; B1 = cd[tb * TILE + 64 + lane];
        }
        int s = wave;
        while (s < ns) {
            {
                const int tn = (s + 8 < ns) ? (int)(slist[s + 8] & 0xFFu) : ownt;
                APPEND_BATCH(A0);
                APPEND_BATCH(A1);
                A0 = cd[tn * TILE + lane]; A1 = cd[tn * TILE + 64 + lane];
                s += 4;
                if (s >= ns) break;
            }
            {
                const int tn = (s + 8 < ns) ? (int)(slist[s + 8] & 0xFFu) : ownt;
                APPEND_BATCH(B0);
                APPEND_BATCH(B1);
                B0 = cd[tn * TILE + lane]; B1 = cd[tn * TILE + 64 + lane];
                s += 4;
            }
        }
    }
    __syncthreads();

    // ---- merge: wave w builds query w's exact lex top-11 ----
    float ld = FLT_MAX; int li = 0x7fffffff;
    float worstm;
    {
        // runtime-wave extraction via select chains (rule: no runtime
        // indexing of register arrays).
        float qxw = qx[0], qyw = qy[0], qzw = qz[0], qsw = qsq[0], wgw = wgate[0];
        if (wave == 1) { qxw = qx[1]; qyw = qy[1]; qzw = qz[1]; qsw = qsq[1]; wgw = wgate[1]; }
        if (wave == 2) { qxw = qx[2]; qyw = qy[2]; qzw = qz[2]; qsw = qsq[2]; wgw = wgate[2]; }
        if (wave == 3) { qxw = qx[3]; qyw = qy[3]; qzw = qz[3]; qsw = qsq[3]; wgw = wgate[3]; }

        const int nq = min(qcur[wave], QCAP);
        const bool ovf = (qovf[wave] != 0);

        if (!ovf) {
            // load queue into registers (6 per lane, FLT_MAX padded)
            float ed[6]; int ei[6];
            #pragma unroll
            for (int j = 0; j < 6; ++j) {
                const int ix = j * 64 + lane;
                const bool in = ix < nq;
                ed[j] = in ? qdq[wave][ix] : FLT_MAX;
                ei[j] = in ? qiq[wave][ix] : 0x7fffffff;
            }
            // radix-select the queue's exact 11th d (nq >= 11 guaranteed:
            // own tile appended >= 11 entries)
            unsigned K[6], pkm = 0u;
            #pragma unroll
            for (int j = 0; j < 6; ++j) {
                const unsigned b = __float_as_uint(ed[j]);
                K[j] = b ^ (((unsigned)((int)b >> 31)) | 0x80000000u);
            }
            for (int b = 31; b >= 0; --b) {
                const unsigned mid = pkm | (1u << b);
                int cnt = 0;
                #pragma unroll
                for (int j = 0; j < 6; ++j)
                    cnt += (int)__popcll(__ballot(K[j] < mid));
                if (cnt < KK) pkm = mid;
            }
            worstm = __uint_as_float(
                (pkm & 0x80000000u) ? (pkm ^ 0x80000000u) : ~pkm);
            // gated serial insert (proven R16 logic, single query)
            #pragma unroll
            for (int j = 0; j < 6; ++j) {
                unsigned long long m = __ballot(ed[j] <= worstm);
                while (m) INS1(ed[j], ei[j], m)
            }
        } else {
            // exact fallback (not expected): serial re-scan of own tile +
            // all survivor tiles for this wave's query.
            worstm = wgw;
            for (int t = -1; t < ns; ++t) {
                const int tl = (t < 0) ? ownt : (int)(slist[t] & 0xFFu);
                #pragma unroll
                for (int h = 0; h < 2; ++h) {
                    const float4 C = cd[tl * TILE + h * 64 + lane];
                    const int ci = __float_as_int(C.w);
                    const float csq_ = __fmaf_rn(C.z, C.z,
                        __fmaf_rn(C.y, C.y, __fmul_rn(C.x, C.x)));
                    float dot = __fmul_rn(C.x, qxw);
                    dot = __fmaf_rn(C.y, qyw, dot);
                    dot = __fmaf_rn(C.z, qzw, dot);
                    const float d = __fmaf_rn(dot, -2.0f, __fadd_rn(qsw, csq_));
                    unsigned long long m = __ballot(d <= worstm);
                    while (m) INS1(d, ci, m)
                }
            }
        }
    }

    // ---- output: wave w writes query w ----
    // Rank 0 (lex-smallest: self or -1ulp near-twin) dropped positionally.
    // Ranks 1..10 -> feature columns 0..9 (reference's quirky gather).
    float fv = -FLT_MAX;
    if (lane >= 1 && lane < KK)
        fv = feats[(size_t)li * C_FEAT + (lane - 1)];
    #pragma unroll
    for (int off = 1; off < 16; off <<= 1)
        fv = fmaxf(fv, __shfl_xor(fv, off));
    const float M = __shfl(fv, 0);

    int row = qor[0];
    if (wave == 1) row = qor[1];
    if (wave == 2) row = qor[2];
    if (wave == 3) row = qor[3];
    const float v = feats[(size_t)row * C_FEAT + lane];
    outb[(size_t)row * (2 * C_FEAT) + lane]          = v;
    outb[(size_t)row * (2 * C_FEAT) + C_FEAT + lane] = M - v;
}

extern "C" void kernel_launch(void* const* d_in, const int* in_sizes, int n_in,
                              void* d_out, int out_size, void* d_ws, size_t ws_size,
                              hipStream_t stream) {
    const float* src_f = (const float*)d_in[0];
    const float* tgt_f = (const float*)d_in[1];
    const float* src_c = (const float*)d_in[2];
    const float* tgt_c = (const float*)d_in[3];
    float* out = (float*)d_out;

    char* ws = (char*)d_ws;
    float4* cand = (float4*)(ws + WS_CAND);
    float*  aabb = (float*) (ws + WS_AABB);
    int*    hist = (int*)   (ws + WS_HIST);

    hipMemsetAsync(hist, 0, 2 * NCELLS * sizeof(int), stream);
    hipLaunchKernelGGL(hist_kernel, dim3(128), dim3(256), 0, stream,
                       src_c, tgt_c, hist);
    hipLaunchKernelGGL(scan_kernel, dim3(2), dim3(1024), 0, stream, hist);
    hipLaunchKernelGGL(scatter_kernel, dim3(128), dim3(256), 0, stream,
                       src_c, tgt_c, hist, cand);
    hipLaunchKernelGGL(aabb_kernel, dim3(2 * NTILES), dim3(64), 0, stream,
                       cand, aabb);
    hipLaunchKernelGGL(knn_pool_kernel, dim3(2 * (N_PTS / QPB)), dim3(NTHREADS),
                       0, stream, src_f, tgt_f, cand, aabb, out);
}

// Round 11
// 195.112 us; speedup vs baseline: 1.3753x; 1.3753x over previous
//
#include <hip/hip_runtime.h>
#include <cfloat>
#include <math.h>

// Exact-replication KNN (k=10, +self) + rank-column gather max-pool.
// NUMERICS FROZEN (R3 pass, absmax 0.0): fp32 chains
//   sq  = fma(z,z, fma(y,y, rn(x*x)))
//   dot = fma(z,z', fma(y,y', rn(x*x')))
//   d   = fma(dot, -2, rn(sq_i+sq_j))    [== rn(sum - rn(2*dot)), 2*dot exact]
// Selection order = jax top_k = ascending lexicographic (d, orig_idx) —
// proven order-independent in R8/R9 (absmax 0.0, nondeterministic scatter).
//
// Round 21: revert to R16 (best verified, wall 195.6 / knn 119.4) after the
// R20 gate-and-append regression (FETCH 10->98 MB: QPB=4 streaming killed
// L2 locality; overflow fallback fired). Single change vs R16: retest the
// DPP row_shr:1 substitution for the two ds_bpermute ops in the insert
// chain. R12 tested it pre-R14 and lost (inserts were 4x more numerous and
// sat in the full-occupancy init phase where VALU contention rules). Post-
// R14 the inserts are few and live in the occupancy-DECAYED scan phase
// (VALUBusy 38% = idle issue slots, exposed LDS latency) -> the ~50cy
// bpermute round-trips on the serial chain should now cost more than the
// extra VALU ops. Substitution proven bit-identical in R12 (lrank==0 keeps
// 'old', which the fst select already ignores; absmax 0.0).

#define N_PTS    16384
#define C_FEAT   64
#define KK       11
#define NCELLS   4096                 // 16^3 Morton cells
#define TILE     128                  // sorted points per tile
#define NTILES   (N_PTS / TILE)       // 128
#define WQ       4
#define NWAVES   4
#define NTHREADS (NWAVES * 64)
#define QPB      (NWAVES * WQ)        // 16 queries per block

// d_ws layout (bytes)
#define WS_CAND  0                            // float4[2][N_PTS]   512 KB
#define WS_AABB  (WS_CAND + 2*N_PTS*16)       // float[2][NTILES][6]  6 KB
#define WS_HIST  (WS_AABB + 2*NTILES*6*4)     // int[2][NCELLS]      32 KB

__device__ __forceinline__ int cell_of(float x, float y, float z) {
    int cx = (int)floorf((x + 4.5f) * (16.0f / 9.0f));
    int cy = (int)floorf((y + 4.5f) * (16.0f / 9.0f));
    int cz = (int)floorf((z + 4.5f) * (16.0f / 9.0f));
    cx = min(15, max(0, cx));
    cy = min(15, max(0, cy));
    cz = min(15, max(0, cz));
    int m = 0;
    #pragma unroll
    for (int b = 0; b < 4; ++b)
        m |= (((cx >> b) & 1) << (3 * b)) |
             (((cy >> b) & 1) << (3 * b + 1)) |
             (((cz >> b) & 1) << (3 * b + 2));
    return m;
}

// 128 blocks x 256 thr, one point per thread. Global atomics into hist
// (pre-zeroed by hipMemsetAsync).
__global__ __launch_bounds__(256) void hist_kernel(
    const float* __restrict__ src_c, const float* __restrict__ tgt_c,
    int* __restrict__ hist)
{
    const int inst = blockIdx.x >> 6;           // 64 blocks per instance
    const float* __restrict__ coords = inst ? tgt_c : src_c;
    int* __restrict__ h = hist + inst * NCELLS;
    const int p = ((blockIdx.x & 63) << 8) + threadIdx.x;
    const float* c = coords + (size_t)p * 3;
    atomicAdd(&h[cell_of(c[0], c[1], c[2])], 1);
}

// One block per instance. Barrier scan; leaves h[cell] = exclusive base.
__global__ __launch_bounds__(1024) void scan_kernel(int* __restrict__ hist)
{
    const int inst = blockIdx.x;
    int* __restrict__ h = hist + inst * NCELLS;
    __shared__ int sd[1024];
    const int t = threadIdx.x;

    int v[4], ssum = 0;
    #pragma unroll
    for (int j = 0; j < 4; ++j) { v[j] = h[t * 4 + j]; ssum += v[j]; }
    sd[t] = ssum;
    __syncthreads();
    for (int off = 1; off < 1024; off <<= 1) {
        const int x = (t >= off) ? sd[t - off] : 0;
        __syncthreads();
        sd[t] += x;
        __syncthreads();
    }
    int base = sd[t] - ssum;
    #pragma unroll
    for (int j = 0; j < 4; ++j) { h[t * 4 + j] = base; base += v[j]; }
}

// 128 blocks x 256 thr. dst = atomicAdd(write-pointer). Within-cell order is
// nondeterministic — exactly as R8-R20 (selection proven order-independent).
__global__ __launch_bounds__(256) void scatter_kernel(
    const float* __restrict__ src_c, const float* __restrict__ tgt_c,
    int* __restrict__ hist, float4* __restrict__ cand)
{
    const int inst = blockIdx.x >> 6;
    const float* __restrict__ coords = inst ? tgt_c : src_c;
    int* __restrict__ h = hist + inst * NCELLS;
    float4* __restrict__ cb = cand + inst * N_PTS;
    const int p = ((blockIdx.x & 63) << 8) + threadIdx.x;
    const float* c = coords + (size_t)p * 3;
    const float x = c[0], y = c[1], z = c[2];
    const int dst = atomicAdd(&h[cell_of(x, y, z)], 1);
    cb[dst] = make_float4(x, y, z, __int_as_float(p));
}

__global__ void aabb_kernel(const float4* __restrict__ cand,
                            float* __restrict__ aabb) {
    const int it = blockIdx.x;                 // inst*NTILES + tile
    const int base = (it / NTILES) * N_PTS + (it % NTILES) * TILE;
    const int lane = threadIdx.x;              // 64 threads, 2 pts each
    float4 a = cand[base + lane], b = cand[base + 64 + lane];
    float mnx = fminf(a.x, b.x), mny = fminf(a.y, b.y), mnz = fminf(a.z, b.z);
    float mxx = fmaxf(a.x, b.x), mxy = fmaxf(a.y, b.y), mxz = fmaxf(a.z, b.z);
    #pragma unroll
    for (int off = 1; off < 64; off <<= 1) {
        mnx = fminf(mnx, __shfl_xor(mnx, off));
        mny = fminf(mny, __shfl_xor(mny, off));
        mnz = fminf(mnz, __shfl_xor(mnz, off));
        mxx = fmaxf(mxx, __shfl_xor(mxx, off));
        mxy = fmaxf(mxy, __shfl_xor(mxy, off));
        mxz = fmaxf(mxz, __shfl_xor(mxz, off));
    }
    if (lane == 0) {
        aabb[it * 6 + 0] = mnx; aabb[it * 6 + 1] = mny; aabb[it * 6 + 2] = mnz;
        aabb[it * 6 + 3] = mxx; aabb[it * 6 + 4] = mxy; aabb[it * 6 + 5] = mxz;
    }
}

// lane lrank-1's value within the 16-lane row, 1-cycle VALU (DPP row_shr:1).
// Lanes with lrank==0 keep 'old' — callers ignore those (fst forced true).
__device__ __forceinline__ int shup16_i(int v) {
    return __builtin_amdgcn_update_dpp(v, v, 0x111, 0xf, 0xf, false);
}
__device__ __forceinline__ float shup16_f(float v) {
    return __int_as_float(
        __builtin_amdgcn_update_dpp(__float_as_int(v), __float_as_int(v),
                                    0x111, 0xf, 0xf, false));
}

// Frozen distance chain for candidate C vs query q (do not reorder).
#define DIST_TO(C, q, dout)                                                 \
  { const float csq_ = __fmaf_rn((C).z, (C).z, __fmaf_rn((C).y, (C).y,      \
                                 __fmul_rn((C).x, (C).x)));                 \
    float dot_ = __fmul_rn((C).x, qx[q]);                                   \
    dot_ = __fmaf_rn((C).y, qy[q], dot_);                                   \
    dot_ = __fmaf_rn((C).z, qz[q], dot_);                                   \
    (dout) = __fmaf_rn(dot_, -2.0f, __fadd_rn(qsq[q], csq_)); }

// One 64-candidate batch vs the wave's 4 queries (proven in R8/R9).
// Insert chain uses DPP row_shr:1 (see shup16_*) instead of ds_bpermute.
#define PROCESS_BATCH(C)                                                    \
  {                                                                         \
    const float cx = (C).x, cy = (C).y, cz = (C).z;                         \
    const int corig = __float_as_int((C).w);                                \
    const float csq = __fmaf_rn(cz, cz, __fmaf_rn(cy, cy,                   \
                                __fmul_rn(cx, cx)));                        \
    _Pragma("unroll")                                                       \
    for (int q = 0; q < WQ; ++q) {                                          \
      float dot = __fmul_rn(cx, qx[q]);                                     \
      dot = __fmaf_rn(cy, qy[q], dot);                                      \
      dot = __fmaf_rn(cz, qz[q], dot);                                      \
      const float sum = __fadd_rn(qsq[q], csq);                             \
      const float d = __fmaf_rn(dot, -2.0f, sum);                           \
      unsigned long long m = __ballot(d <= worst[q]);                       \
      while (m) {                                                           \
        const int sl = (int)__builtin_ctzll(m);                             \
        m &= m - 1;                                                         \
        const float nd = __int_as_float(__builtin_amdgcn_readlane(          \
            __float_as_int(d), sl));                                        \
        if (nd <= worst[q]) {                                               \
          const int norig = __builtin_amdgcn_readlane(corig, sl);           \
          const float pld = shup16_f(ld);                                   \
          const int   pli = shup16_i(li);                                   \
          const bool gt = (ld > nd) || (ld == nd && li > norig);            \
          if (ingrp[q] && gt) {                                             \
            const bool pgt = (pld > nd) || (pld == nd && pli > norig);      \
            const bool fst = (lrank == 0) || (!pgt);                        \
            ld = fst ? nd : pld;                                            \
            li = fst ? norig : pli;                                         \
          }                                                                 \
          worst[q] = fminf(worst[q],                                        \
              __int_as_float(__builtin_amdgcn_readlane(                     \
                  __float_as_int(ld), q * 16 + (KK - 1))));                 \
        }                                                                   \
      }                                                                     \
    }                                                                       \
  }

#define WMAX4 fmaxf(fmaxf(worst[0], worst[1]), fmaxf(worst[2], worst[3]))

__global__ __launch_bounds__(NTHREADS) void knn_pool_kernel(
    const float* __restrict__ src_f, const float* __restrict__ tgt_f,
    const float4* __restrict__ cand, const float* __restrict__ aabb,
    float* __restrict__ out)
{
    const int inst = blockIdx.x & 1;
    const float* __restrict__ feats = inst ? tgt_f : src_f;
    float* __restrict__ outb = out + (size_t)inst * N_PTS * (2 * C_FEAT);
    const float4* __restrict__ cd = cand + inst * N_PTS;

    const int tid = threadIdx.x, wave = tid >> 6, lane = tid & 63;
    const int lq = lane >> 4, lrank = lane & 15;
    const bool inlist = (lrank < KK);

    __shared__ float sab[NTILES * 6];                 // 3 KB
    __shared__ unsigned int slist[NWAVES][NTILES];    // packed (lb|tile), 2 KB
    for (int i = tid; i < NTILES * 6; i += NTHREADS)
        sab[i] = aabb[inst * NTILES * 6 + i];
    __syncthreads();

    const int q0 = (blockIdx.x >> 1) * QPB + wave * WQ;  // sorted row
    float qx[WQ], qy[WQ], qz[WQ], qsq[WQ];
    int qor[WQ]; bool ingrp[WQ]; float worst[WQ];
    float wqmnx = FLT_MAX, wqmny = FLT_MAX, wqmnz = FLT_MAX;
    float wqmxx = -FLT_MAX, wqmxy = -FLT_MAX, wqmxz = -FLT_MAX;
    #pragma unroll
    for (int q = 0; q < WQ; ++q) {
        const float4 c = cd[q0 + q];
        qx[q] = c.x; qy[q] = c.y; qz[q] = c.z;
        qor[q] = __float_as_int(c.w);
        qsq[q] = __fmaf_rn(c.z, c.z, __fmaf_rn(c.y, c.y, __fmul_rn(c.x, c.x)));
        ingrp[q] = inlist && (lq == q);
        worst[q] = FLT_MAX;
        wqmnx = fminf(wqmnx, c.x); wqmxx = fmaxf(wqmxx, c.x);
        wqmny = fminf(wqmny, c.y); wqmxy = fmaxf(wqmxy, c.y);
        wqmnz = fminf(wqmnz, c.z); wqmxz = fmaxf(wqmxz, c.z);
    }

    float ld = FLT_MAX;   // lane-distributed sorted list (lex (d, orig_idx))
    int   li = 0x7fffffff;

    const int ownt = q0 / TILE;   // tile containing the queries

    // ---- own tile: radix-select exact 11th distance -> tight worst init --
    {
        const float4 c0 = cd[ownt * TILE + lane];
        const float4 c1 = cd[ownt * TILE + 64 + lane];

        // Order-preserving uint keys of the frozen fp32 distances
        // (bijective; handles the -eps self-distance sign case).
        unsigned k0[WQ], k1[WQ], pk[WQ];
        #pragma unroll
        for (int q = 0; q < WQ; ++q) {
            float d0, d1;
            DIST_TO(c0, q, d0);
            DIST_TO(c1, q, d1);
            const unsigned b0 = __float_as_uint(d0), b1 = __float_as_uint(d1);
            k0[q] = b0 ^ (((unsigned)((int)b0 >> 31)) | 0x80000000u);
            k1[q] = b1 ^ (((unsigned)((int)b1 >> 31)) | 0x80000000u);
            pk[q] = 0u;
        }
        // MSB->LSB bisection: after the loop pk[q] == key of the exact
        // 11th-smallest (counting multiplicity) of the 128 own-tile dists.
        for (int b = 31; b >= 0; --b) {
            #pragma unroll
            for (int q = 0; q < WQ; ++q) {
                const unsigned mid = pk[q] | (1u << b);
                const int cnt = (int)__popcll(__ballot(k0[q] < mid))
                              + (int)__popcll(__ballot(k1[q] < mid));
                if (cnt < KK) pk[q] = mid;
            }
        }
        #pragma unroll
        for (int q = 0; q < WQ; ++q) {
            const unsigned p = pk[q];
            worst[q] = __uint_as_float(
                (p & 0x80000000u) ? (p ^ 0x80000000u) : ~p);
        }
        // Gated batches: m now has ~11+ties bits total; the serial insert
        // (unchanged logic) rebuilds the exact lex-sorted list.
        PROCESS_BATCH(c0);
        PROCESS_BATCH(c1);
    }
    const float wmax0 = WMAX4;

    // ---- zigzag (near->far) survivor list, built in parallel ----
    // entry = (float_bits(lb) & ~0xFF) | tile  — lb>=0 so uint order == lb
    // order; unpacked lb rounds DOWN => recheck skip stays conservative.
    int nsurv = 0;
    #pragma unroll
    for (int g = 0; g < 4; ++g) {
        const int p = g * 64 + lane;
        const int o = (p >> 1) + 1;
        const int t = (p & 1) ? (ownt - o) : (ownt + o);
        bool ok = (t >= 0) && (t < NTILES);
        float lb = 0.0f;
        if (ok) {
            const float dx = fmaxf(0.f, fmaxf(sab[t*6+0] - wqmxx, wqmnx - sab[t*6+3]));
            const float dy = fmaxf(0.f, fmaxf(sab[t*6+1] - wqmxy, wqmny - sab[t*6+4]));
            const float dz = fmaxf(0.f, fmaxf(sab[t*6+2] - wqmxz, wqmnz - sab[t*6+5]));
            lb = dx * dx;
            lb = fmaf(dy, dy, lb);
            lb = fmaf(dz, dz, lb);
            ok = (lb - 1e-3f) <= wmax0;   // margin >> fp32 chain error
        }
        const unsigned long long mk = __ballot(ok);
        if (ok) {
            const int idx = nsurv + (int)__popcll(mk & ((1ull << lane) - 1ull));
            slist[wave][idx] = (__float_as_uint(lb) & 0xFFFFFF00u) | (unsigned)t;
        }
        nsurv += (int)__popcll(mk);
    }

    // ---- scan survivors: 4-slot prefetch ring + LIVE recheck vs wmax ----
    // Loads for slot s issue while slot s-4 is processed (~3 tiles of
    // latency cover for the occupancy-decayed tail regime). Tail slots
    // prefetch ownt harmlessly (never processed: loop bound).
    float4 T0a, T0b, T1a, T1b, T2a, T2b, T3a, T3b;
    unsigned int u0 = 0, u1 = 0, u2 = 0, u3 = 0;
    {
        u0 = (0 < nsurv) ? slist[wave][0] : (unsigned)ownt;
        const int t0 = (int)(u0 & 0xFFu);
        T0a = cd[t0 * TILE + lane]; T0b = cd[t0 * TILE + 64 + lane];
        u1 = (1 < nsurv) ? slist[wave][1] : (unsigned)ownt;
        const int t1 = (int)(u1 & 0xFFu);
        T1a = cd[t1 * TILE + lane]; T1b = cd[t1 * TILE + 64 + lane];
        u2 = (2 < nsurv) ? slist[wave][2] : (unsigned)ownt;
        const int t2 = (int)(u2 & 0xFFu);
        T2a = cd[t2 * TILE + lane]; T2b = cd[t2 * TILE + 64 + lane];
        u3 = (3 < nsurv) ? slist[wave][3] : (unsigned)ownt;
        const int t3 = (int)(u3 & 0xFFu);
        T3a = cd[t3 * TILE + lane]; T3b = cd[t3 * TILE + 64 + lane];
    }
    #define SCAN_STEP(UA, TA, TB)                                           \
      {                                                                     \
        const unsigned uN = (s + 4 < nsurv) ? slist[wave][s + 4]            \
                                            : (unsigned)ownt;               \
        const int tn = (int)(uN & 0xFFu);                                   \
        if (__uint_as_float(UA & 0xFFFFFF00u) - 1e-3f <= WMAX4) {           \
            PROCESS_BATCH(TA);                                              \
            PROCESS_BATCH(TB);                                              \
        }                                                                   \
        UA = uN;                                                            \
        TA = cd[tn * TILE + lane]; TB = cd[tn * TILE + 64 + lane];          \
        ++s;                                                                \
      }
    int s = 0;
    while (s < nsurv) {
        SCAN_STEP(u0, T0a, T0b);
        if (s >= nsurv) break;
        SCAN_STEP(u1, T1a, T1b);
        if (s >= nsurv) break;
        SCAN_STEP(u2, T2a, T2b);
        if (s >= nsurv) break;
        SCAN_STEP(u3, T3a, T3b);
    }
    #undef SCAN_STEP

    // Rank 0 (lex-smallest: self or -1ulp near-twin) dropped positionally.
    // Ranks 1..10 -> feature columns 0..9. li holds ORIGINAL indices.
    float fv = -FLT_MAX;
    if (inlist && lrank >= 1)
        fv = feats[(size_t)li * C_FEAT + (lrank - 1)];
    #pragma unroll
    for (int off = 1; off < 16; off <<= 1)
        fv = fmaxf(fv, __shfl_xor(fv, off));

    #pragma unroll
    for (int q = 0; q < WQ; ++q) {
        const float M   = __shfl(fv, q * 16);
        const int   row = qor[q];
        const float v   = feats[(size_t)row * C_FEAT + lane];
        outb[(size_t)row * (2 * C_FEAT) + lane]          = v;
        outb[(size_t)row * (2 * C_FEAT) + C_FEAT + lane] = M - v;
    }
}

extern "C" void kernel_launch(void* const* d_in, const int* in_sizes, int n_in,
                              void* d_out, int out_size, void* d_ws, size_t ws_size,
                              hipStream_t stream) {
    const float* src_f = (const float*)d_in[0];
    const float* tgt_f = (const float*)d_in[1];
    const float* src_c = (const float*)d_in[2];
    const float* tgt_c = (const float*)d_in[3];
    float* out = (float*)d_out;

    char* ws = (char*)d_ws;
    float4* cand = (float4*)(ws + WS_CAND);
    float*  aabb = (float*) (ws + WS_AABB);
    int*    hist = (int*)   (ws + WS_HIST);

    hipMemsetAsync(hist, 0, 2 * NCELLS * sizeof(int), stream);
    hipLaunchKernelGGL(hist_kernel, dim3(128), dim3(256), 0, stream,
                       src_c, tgt_c, hist);
    hipLaunchKernelGGL(scan_kernel, dim3(2), dim3(1024), 0, stream, hist);
    hipLaunchKernelGGL(scatter_kernel, dim3(128), dim3(256), 0, stream,
                       src_c, tgt_c, hist, cand);
    hipLaunchKernelGGL(aabb_kernel, dim3(2 * NTILES), dim3(64), 0, stream,
                       cand, aabb);
    hipLaunchKernelGGL(knn_pool_kernel, dim3(2 * (N_PTS / QPB)), dim3(NTHREADS),
                       0, stream, src_f, tgt_f, cand, aabb, out);
}

// Round 12
// 189.106 us; speedup vs baseline: 1.4190x; 1.0318x over previous
//
#include <hip/hip_runtime.h>
#include <cfloat>
#include <math.h>

// Exact-replication KNN (k=10, +self) + rank-column gather max-pool.
// NUMERICS FROZEN (R3 pass, absmax 0.0): fp32 chains
//   sq  = fma(z,z, fma(y,y, rn(x*x)))
//   dot = fma(z,z', fma(y,y', rn(x*x')))
//   d   = fma(dot, -2, rn(sq_i+sq_j))    [== rn(sum - rn(2*dot)), 2*dot exact]
// Selection order = jax top_k = ascending lexicographic (d, orig_idx) —
// proven order-independent in R8/R9 (absmax 0.0, nondeterministic scatter).
//
// Round 22: PER-QUERY AABB gating. R21 (DPP insert on post-R14 base) gave
// knn 119->117; kept. The remaining tail waves are those whose 4 queries
// straddle a Morton discontinuity: the UNION query box spans a huge region
// -> lb~0 for all tiles in between -> nsurv ~100+ and a ~117us wave while
// the mean wave is 34us. Now the survivor gate computes point-to-box lb
// PER QUERY and keeps a tile iff exists q: lb_q - eps <= worst[q] (tighter
// on both axes than union-box vs max_q worst). Survivor entries pack
// min_q lb_q; live recheck (minlb > WMAX4 => forall q: lb_q > worst[q])
// stays conservative. Build-skipped tiles satisfy lb_q > worst_q(init) >=
// worst_q(final) for all q -> cannot hold a final top-11 member. Scan
// order + insert logic untouched -> bit-identical selection.

#define N_PTS    16384
#define C_FEAT   64
#define KK       11
#define NCELLS   4096                 // 16^3 Morton cells
#define TILE     128                  // sorted points per tile
#define NTILES   (N_PTS / TILE)       // 128
#define WQ       4
#define NWAVES   4
#define NTHREADS (NWAVES * 64)
#define QPB      (NWAVES * WQ)        // 16 queries per block

// d_ws layout (bytes)
#define WS_CAND  0                            // float4[2][N_PTS]   512 KB
#define WS_AABB  (WS_CAND + 2*N_PTS*16)       // float[2][NTILES][6]  6 KB
#define WS_HIST  (WS_AABB + 2*NTILES*6*4)     // int[2][NCELLS]      32 KB

__device__ __forceinline__ int cell_of(float x, float y, float z) {
    int cx = (int)floorf((x + 4.5f) * (16.0f / 9.0f));
    int cy = (int)floorf((y + 4.5f) * (16.0f / 9.0f));
    int cz = (int)floorf((z + 4.5f) * (16.0f / 9.0f));
    cx = min(15, max(0, cx));
    cy = min(15, max(0, cy));
    cz = min(15, max(0, cz));
    int m = 0;
    #pragma unroll
    for (int b = 0; b < 4; ++b)
        m |= (((cx >> b) & 1) << (3 * b)) |
             (((cy >> b) & 1) << (3 * b + 1)) |
             (((cz >> b) & 1) << (3 * b + 2));
    return m;
}

// 128 blocks x 256 thr, one point per thread. Global atomics into hist
// (pre-zeroed by hipMemsetAsync).
__global__ __launch_bounds__(256) void hist_kernel(
    const float* __restrict__ src_c, const float* __restrict__ tgt_c,
    int* __restrict__ hist)
{
    const int inst = blockIdx.x >> 6;           // 64 blocks per instance
    const float* __restrict__ coords = inst ? tgt_c : src_c;
    int* __restrict__ h = hist + inst * NCELLS;
    const int p = ((blockIdx.x & 63) << 8) + threadIdx.x;
    const float* c = coords + (size_t)p * 3;
    atomicAdd(&h[cell_of(c[0], c[1], c[2])], 1);
}

// One block per instance. Barrier scan; leaves h[cell] = exclusive base.
__global__ __launch_bounds__(1024) void scan_kernel(int* __restrict__ hist)
{
    const int inst = blockIdx.x;
    int* __restrict__ h = hist + inst * NCELLS;
    __shared__ int sd[1024];
    const int t = threadIdx.x;

    int v[4], ssum = 0;
    #pragma unroll
    for (int j = 0; j < 4; ++j) { v[j] = h[t * 4 + j]; ssum += v[j]; }
    sd[t] = ssum;
    __syncthreads();
    for (int off = 1; off < 1024; off <<= 1) {
        const int x = (t >= off) ? sd[t - off] : 0;
        __syncthreads();
        sd[t] += x;
        __syncthreads();
    }
    int base = sd[t] - ssum;
    #pragma unroll
    for (int j = 0; j < 4; ++j) { h[t * 4 + j] = base; base += v[j]; }
}

// 128 blocks x 256 thr. dst = atomicAdd(write-pointer). Within-cell order is
// nondeterministic — exactly as R8-R21 (selection proven order-independent).
__global__ __launch_bounds__(256) void scatter_kernel(
    const float* __restrict__ src_c, const float* __restrict__ tgt_c,
    int* __restrict__ hist, float4* __restrict__ cand)
{
    const int inst = blockIdx.x >> 6;
    const float* __restrict__ coords = inst ? tgt_c : src_c;
    int* __restrict__ h = hist + inst * NCELLS;
    float4* __restrict__ cb = cand + inst * N_PTS;
    const int p = ((blockIdx.x & 63) << 8) + threadIdx.x;
    const float* c = coords + (size_t)p * 3;
    const float x = c[0], y = c[1], z = c[2];
    const int dst = atomicAdd(&h[cell_of(x, y, z)], 1);
    cb[dst] = make_float4(x, y, z, __int_as_float(p));
}

__global__ void aabb_kernel(const float4* __restrict__ cand,
                            float* __restrict__ aabb) {
    const int it = blockIdx.x;                 // inst*NTILES + tile
    const int base = (it / NTILES) * N_PTS + (it % NTILES) * TILE;
    const int lane = threadIdx.x;              // 64 threads, 2 pts each
    float4 a = cand[base + lane], b = cand[base + 64 + lane];
    float mnx = fminf(a.x, b.x), mny = fminf(a.y, b.y), mnz = fminf(a.z, b.z);
    float mxx = fmaxf(a.x, b.x), mxy = fmaxf(a.y, b.y), mxz = fmaxf(a.z, b.z);
    #pragma unroll
    for (int off = 1; off < 64; off <<= 1) {
        mnx = fminf(mnx, __shfl_xor(mnx, off));
        mny = fminf(mny, __shfl_xor(mny, off));
        mnz = fminf(mnz, __shfl_xor(mnz, off));
        mxx = fmaxf(mxx, __shfl_xor(mxx, off));
        mxy = fmaxf(mxy, __shfl_xor(mxy, off));
        mxz = fmaxf(mxz, __shfl_xor(mxz, off));
    }
    if (lane == 0) {
        aabb[it * 6 + 0] = mnx; aabb[it * 6 + 1] = mny; aabb[it * 6 + 2] = mnz;
        aabb[it * 6 + 3] = mxx; aabb[it * 6 + 4] = mxy; aabb[it * 6 + 5] = mxz;
    }
}

// lane lrank-1's value within the 16-lane row, 1-cycle VALU (DPP row_shr:1).
// Lanes with lrank==0 keep 'old' — callers ignore those (fst forced true).
__device__ __forceinline__ int shup16_i(int v) {
    return __builtin_amdgcn_update_dpp(v, v, 0x111, 0xf, 0xf, false);
}
__device__ __forceinline__ float shup16_f(float v) {
    return __int_as_float(
        __builtin_amdgcn_update_dpp(__float_as_int(v), __float_as_int(v),
                                    0x111, 0xf, 0xf, false));
}

// Frozen distance chain for candidate C vs query q (do not reorder).
#define DIST_TO(C, q, dout)                                                 \
  { const float csq_ = __fmaf_rn((C).z, (C).z, __fmaf_rn((C).y, (C).y,      \
                                 __fmul_rn((C).x, (C).x)));                 \
    float dot_ = __fmul_rn((C).x, qx[q]);                                   \
    dot_ = __fmaf_rn((C).y, qy[q], dot_);                                   \
    dot_ = __fmaf_rn((C).z, qz[q], dot_);                                   \
    (dout) = __fmaf_rn(dot_, -2.0f, __fadd_rn(qsq[q], csq_)); }

// One 64-candidate batch vs the wave's 4 queries (proven in R8/R9).
// Insert chain uses DPP row_shr:1 (see shup16_*) — R21, kept.
#define PROCESS_BATCH(C)                                                    \
  {                                                                         \
    const float cx = (C).x, cy = (C).y, cz = (C).z;                         \
    const int corig = __float_as_int((C).w);                                \
    const float csq = __fmaf_rn(cz, cz, __fmaf_rn(cy, cy,                   \
                                __fmul_rn(cx, cx)));                        \
    _Pragma("unroll")                                                       \
    for (int q = 0; q < WQ; ++q) {                                          \
      float dot = __fmul_rn(cx, qx[q]);                                     \
      dot = __fmaf_rn(cy, qy[q], dot);                                      \
      dot = __fmaf_rn(cz, qz[q], dot);                                      \
      const float sum = __fadd_rn(qsq[q], csq);                             \
      const float d = __fmaf_rn(dot, -2.0f, sum);                           \
      unsigned long long m = __ballot(d <= worst[q]);                       \
      while (m) {                                                           \
        const int sl = (int)__builtin_ctzll(m);                             \
        m &= m - 1;                                                         \
        const float nd = __int_as_float(__builtin_amdgcn_readlane(          \
            __float_as_int(d), sl));                                        \
        if (nd <= worst[q]) {                                               \
          const int norig = __builtin_amdgcn_readlane(corig, sl);           \
          const float pld = shup16_f(ld);                                   \
          const int   pli = shup16_i(li);                                   \
          const bool gt = (ld > nd) || (ld == nd && li > norig);            \
          if (ingrp[q] && gt) {                                             \
            const bool pgt = (pld > nd) || (pld == nd && pli > norig);      \
            const bool fst = (lrank == 0) || (!pgt);                        \
            ld = fst ? nd : pld;                                            \
            li = fst ? norig : pli;                                         \
          }                                                                 \
          worst[q] = fminf(worst[q],                                        \
              __int_as_float(__builtin_amdgcn_readlane(                     \
                  __float_as_int(ld), q * 16 + (KK - 1))));                 \
        }                                                                   \
      }                                                                     \
    }                                                                       \
  }

#define WMAX4 fmaxf(fmaxf(worst[0], worst[1]), fmaxf(worst[2], worst[3]))

__global__ __launch_bounds__(NTHREADS) void knn_pool_kernel(
    const float* __restrict__ src_f, const float* __restrict__ tgt_f,
    const float4* __restrict__ cand, const float* __restrict__ aabb,
    float* __restrict__ out)
{
    const int inst = blockIdx.x & 1;
    const float* __restrict__ feats = inst ? tgt_f : src_f;
    float* __restrict__ outb = out + (size_t)inst * N_PTS * (2 * C_FEAT);
    const float4* __restrict__ cd = cand + inst * N_PTS;

    const int tid = threadIdx.x, wave = tid >> 6, lane = tid & 63;
    const int lq = lane >> 4, lrank = lane & 15;
    const bool inlist = (lrank < KK);

    __shared__ float sab[NTILES * 6];                 // 3 KB
    __shared__ unsigned int slist[NWAVES][NTILES];    // packed (lb|tile), 2 KB
    for (int i = tid; i < NTILES * 6; i += NTHREADS)
        sab[i] = aabb[inst * NTILES * 6 + i];
    __syncthreads();

    const int q0 = (blockIdx.x >> 1) * QPB + wave * WQ;  // sorted row
    float qx[WQ], qy[WQ], qz[WQ], qsq[WQ];
    int qor[WQ]; bool ingrp[WQ]; float worst[WQ];
    #pragma unroll
    for (int q = 0; q < WQ; ++q) {
        const float4 c = cd[q0 + q];
        qx[q] = c.x; qy[q] = c.y; qz[q] = c.z;
        qor[q] = __float_as_int(c.w);
        qsq[q] = __fmaf_rn(c.z, c.z, __fmaf_rn(c.y, c.y, __fmul_rn(c.x, c.x)));
        ingrp[q] = inlist && (lq == q);
        worst[q] = FLT_MAX;
    }

    float ld = FLT_MAX;   // lane-distributed sorted list (lex (d, orig_idx))
    int   li = 0x7fffffff;

    const int ownt = q0 / TILE;   // tile containing the queries

    // ---- own tile: radix-select exact 11th distance -> tight worst init --
    {
        const float4 c0 = cd[ownt * TILE + lane];
        const float4 c1 = cd[ownt * TILE + 64 + lane];

        // Order-preserving uint keys of the frozen fp32 distances
        // (bijective; handles the -eps self-distance sign case).
        unsigned k0[WQ], k1[WQ], pk[WQ];
        #pragma unroll
        for (int q = 0; q < WQ; ++q) {
            float d0, d1;
            DIST_TO(c0, q, d0);
            DIST_TO(c1, q, d1);
            const unsigned b0 = __float_as_uint(d0), b1 = __float_as_uint(d1);
            k0[q] = b0 ^ (((unsigned)((int)b0 >> 31)) | 0x80000000u);
            k1[q] = b1 ^ (((unsigned)((int)b1 >> 31)) | 0x80000000u);
            pk[q] = 0u;
        }
        // MSB->LSB bisection: after the loop pk[q] == key of the exact
        // 11th-smallest (counting multiplicity) of the 128 own-tile dists.
        for (int b = 31; b >= 0; --b) {
            #pragma unroll
            for (int q = 0; q < WQ; ++q) {
                const unsigned mid = pk[q] | (1u << b);
                const int cnt = (int)__popcll(__ballot(k0[q] < mid))
                              + (int)__popcll(__ballot(k1[q] < mid));
                if (cnt < KK) pk[q] = mid;
            }
        }
        #pragma unroll
        for (int q = 0; q < WQ; ++q) {
            const unsigned p = pk[q];
            worst[q] = __uint_as_float(
                (p & 0x80000000u) ? (p ^ 0x80000000u) : ~p);
        }
        // Gated batches: m now has ~11+ties bits total; the serial insert
        // (unchanged logic) rebuilds the exact lex-sorted list.
        PROCESS_BATCH(c0);
        PROCESS_BATCH(c1);
    }

    // ---- zigzag (near->far) survivor list: PER-QUERY point-to-box lb ----
    // keep tile iff exists q: lb_q - eps <= worst[q] (worst = exact own-tile
    // 11th; final worst only shrinks -> skip is safe). Entry packs
    // minlb = min_q lb_q: (bits & ~0xFF) | tile — minlb>=0 so uint order ==
    // lb order; unpacked value rounds DOWN => recheck stays conservative.
    int nsurv = 0;
    #pragma unroll
    for (int g = 0; g < 4; ++g) {
        const int p = g * 64 + lane;
        const int o = (p >> 1) + 1;
        const int t = (p & 1) ? (ownt - o) : (ownt + o);
        bool ok = (t >= 0) && (t < NTILES);
        float mlb = 0.0f;
        if (ok) {
            const float tmnx = sab[t*6+0], tmny = sab[t*6+1], tmnz = sab[t*6+2];
            const float tmxx = sab[t*6+3], tmxy = sab[t*6+4], tmxz = sab[t*6+5];
            bool any = false;
            mlb = FLT_MAX;
            #pragma unroll
            for (int q = 0; q < WQ; ++q) {
                const float dx = fmaxf(0.f, fmaxf(tmnx - qx[q], qx[q] - tmxx));
                const float dy = fmaxf(0.f, fmaxf(tmny - qy[q], qy[q] - tmxy));
                const float dz = fmaxf(0.f, fmaxf(tmnz - qz[q], qz[q] - tmxz));
                float lb = dx * dx;
                lb = fmaf(dy, dy, lb);
                lb = fmaf(dz, dz, lb);
                any = any || ((lb - 1e-3f) <= worst[q]);
                mlb = fminf(mlb, lb);
            }
            ok = any;
        }
        const unsigned long long mk = __ballot(ok);
        if (ok) {
            const int idx = nsurv + (int)__popcll(mk & ((1ull << lane) - 1ull));
            slist[wave][idx] = (__float_as_uint(mlb) & 0xFFFFFF00u) | (unsigned)t;
        }
        nsurv += (int)__popcll(mk);
    }

    // ---- scan survivors: 4-slot prefetch ring + LIVE recheck vs wmax ----
    // Loads for slot s issue while slot s-4 is processed (~3 tiles of
    // latency cover for the occupancy-decayed tail regime). Tail slots
    // prefetch ownt harmlessly (never processed: loop bound).
    float4 T0a, T0b, T1a, T1b, T2a, T2b, T3a, T3b;
    unsigned int u0 = 0, u1 = 0, u2 = 0, u3 = 0;
    {
        u0 = (0 < nsurv) ? slist[wave][0] : (unsigned)ownt;
        const int t0 = (int)(u0 & 0xFFu);
        T0a = cd[t0 * TILE + lane]; T0b = cd[t0 * TILE + 64 + lane];
        u1 = (1 < nsurv) ? slist[wave][1] : (unsigned)ownt;
        const int t1 = (int)(u1 & 0xFFu);
        T1a = cd[t1 * TILE + lane]; T1b = cd[t1 * TILE + 64 + lane];
        u2 = (2 < nsurv) ? slist[wave][2] : (unsigned)ownt;
        const int t2 = (int)(u2 & 0xFFu);
        T2a = cd[t2 * TILE + lane]; T2b = cd[t2 * TILE + 64 + lane];
        u3 = (3 < nsurv) ? slist[wave][3] : (unsigned)ownt;
        const int t3 = (int)(u3 & 0xFFu);
        T3a = cd[t3 * TILE + lane]; T3b = cd[t3 * TILE + 64 + lane];
    }
    #define SCAN_STEP(UA, TA, TB)                                           \
      {                                                                     \
        const unsigned uN = (s + 4 < nsurv) ? slist[wave][s + 4]            \
                                            : (unsigned)ownt;               \
        const int tn = (int)(uN & 0xFFu);                                   \
        if (__uint_as_float(UA & 0xFFFFFF00u) - 1e-3f <= WMAX4) {           \
            PROCESS_BATCH(TA);                                              \
            PROCESS_BATCH(TB);                                              \
        }                                                                   \
        UA = uN;                                                            \
        TA = cd[tn * TILE + lane]; TB = cd[tn * TILE + 64 + lane];          \
        ++s;                                                                \
      }
    int s = 0;
    while (s < nsurv) {
        SCAN_STEP(u0, T0a, T0b);
        if (s >= nsurv) break;
        SCAN_STEP(u1, T1a, T1b);
        if (s >= nsurv) break;
        SCAN_STEP(u2, T2a, T2b);
        if (s >= nsurv) break;
        SCAN_STEP(u3, T3a, T3b);
    }
    #undef SCAN_STEP

    // Rank 0 (lex-smallest: self or -1ulp near-twin) dropped positionally.
    // Ranks 1..10 -> feature columns 0..9. li holds ORIGINAL indices.
    float fv = -FLT_MAX;
    if (inlist && lrank >= 1)
        fv = feats[(size_t)li * C_FEAT + (lrank - 1)];
    #pragma unroll
    for (int off = 1; off < 16; off <<= 1)
        fv = fmaxf(fv, __shfl_xor(fv, off));

    #pragma unroll
    for (int q = 0; q < WQ; ++q) {
        const float M   = __shfl(fv, q * 16);
        const int   row = qor[q];
        const float v   = feats[(size_t)row * C_FEAT + lane];
        outb[(size_t)row * (2 * C_FEAT) + lane]          = v;
        outb[(size_t)row * (2 * C_FEAT) + C_FEAT + lane] = M - v;
    }
}

extern "C" void kernel_launch(void* const* d_in, const int* in_sizes, int n_in,
                              void* d_out, int out_size, void* d_ws, size_t ws_size,
                              hipStream_t stream) {
    const float* src_f = (const float*)d_in[0];
    const float* tgt_f = (const float*)d_in[1];
    const float* src_c = (const float*)d_in[2];
    const float* tgt_c = (const float*)d_in[3];
    float* out = (float*)d_out;

    char* ws = (char*)d_ws;
    float4* cand = (float4*)(ws + WS_CAND);
    float*  aabb = (float*) (ws + WS_AABB);
    int*    hist = (int*)   (ws + WS_HIST);

    hipMemsetAsync(hist, 0, 2 * NCELLS * sizeof(int), stream);
    hipLaunchKernelGGL(hist_kernel, dim3(128), dim3(256), 0, stream,
                       src_c, tgt_c, hist);
    hipLaunchKernelGGL(scan_kernel, dim3(2), dim3(1024), 0, stream, hist);
    hipLaunchKernelGGL(scatter_kernel, dim3(128), dim3(256), 0, stream,
                       src_c, tgt_c, hist, cand);
    hipLaunchKernelGGL(aabb_kernel, dim3(2 * NTILES), dim3(64), 0, stream,
                       cand, aabb);
    hipLaunchKernelGGL(knn_pool_kernel, dim3(2 * (N_PTS / QPB)), dim3(NTHREADS),
                       0, stream, src_f, tgt_f, cand, aabb, out);
}